// Round 10
// baseline (154.826 us; speedup 1.0000x reference)
//
#include <hip/hip_runtime.h>

typedef _Float16 f16;
typedef f16  f16x4 __attribute__((ext_vector_type(4)));
typedef f16  f16x8 __attribute__((ext_vector_type(8)));
typedef float f32x2  __attribute__((ext_vector_type(2)));
typedef float f32x4  __attribute__((ext_vector_type(4)));
typedef float f32x16 __attribute__((ext_vector_type(16)));
typedef unsigned int u32;
typedef u32 u32x2 __attribute__((ext_vector_type(2)));
typedef u32 u32x4 __attribute__((ext_vector_type(4)));

#define LOG2E   1.4426950408889634f
#define LN2     0.6931471805599453f
#define C_TANH  2.8853900817779268f    // 2*log2(e)
#define C_SIN   0.15915494309189535f   // 1/(2*pi)
#define C_SIG  -1.4426950408889634f    // -log2(e)
#define C_GAU  -0.7213475204444817f    // -log2(e)/2
#define C_GSQ   0.84932180028802f      // sqrt(log2(e)/2): gauss = exp2(-(s*u)^2)

// per-node arg prescale baked into W,b at prep: acts 0=tanh,1=elu,2=softplus,3=sin,4=gauss,5=sigmoid
__device__ __constant__ float NSCL[12] = {
    C_TANH, C_TANH, 1.0f, LOG2E, C_SIN, C_GSQ, C_SIG, C_TANH, 1.0f, LOG2E, C_SIN, C_GSQ
};

__device__ __forceinline__ float frcp(float x){ return __builtin_amdgcn_rcpf(x); }
__device__ __forceinline__ float fexp2(float x){ return __builtin_amdgcn_exp2f(x); }
__device__ __forceinline__ float flog2(float x){ return __builtin_amdgcn_logf(x); }
__device__ __forceinline__ float fsin1(float x){ return __builtin_amdgcn_sinf(x); } // arg in revolutions

// ---------- PAIR-PACKED activations on PRESCALED args (see NSCL) ----------
// r5/r8 calibration: trans ~5-8cy effective, plain packed ~2cy -> trans count
// is floor'd (9/feat input, minimal graph forms); only overlap remains.
template<int A> __device__ __forceinline__ f32x2 act2(f32x2 v){
    if constexpr (A == 0){                       // tanh; v = 2log2e*x
        f32x2 t = {fexp2(v.x), fexp2(v.y)};
        f32x2 u = t + 1.0f;
        f32x2 rc = {frcp(u.x), frcp(u.y)};
        return rc * -2.0f + 1.0f;                // pk_fma
    } else if constexpr (A == 1){                // elu; v raw: max(v,0)+min(e-1,0)
        f32x2 w = v * LOG2E;
        f32x2 e = {fexp2(w.x), fexp2(w.y)};
        f32x2 em1 = e - 1.0f;
        f32x2 z = {0.0f, 0.0f};
        return __builtin_elementwise_max(v, z) + __builtin_elementwise_min(em1, z);
    } else if constexpr (A == 2){                // softplus; v = log2e*x
        f32x2 e = {fexp2(v.x), fexp2(v.y)};
        f32x2 u = e + 1.0f;
        f32x2 l = {flog2(u.x), flog2(u.y)};
        return l * LN2;
    } else if constexpr (A == 3){                // sin; v = x/(2pi)
        return f32x2{fsin1(v.x), fsin1(v.y)};
    } else if constexpr (A == 4){                // gauss; v = sqrt(log2e/2)*x
        f32x2 w = -(v * v);
        return f32x2{fexp2(w.x), fexp2(w.y)};
    } else {                                     // sigmoid; v = -log2e*x
        f32x2 e = {fexp2(v.x), fexp2(v.y)};
        f32x2 u = e + 1.0f;
        return f32x2{frcp(u.x), frcp(u.y)};
    }
}

__device__ __forceinline__ f16x4 pack4(float a, float b, float c, float d){
    u32x2 u;
    u[0] = __builtin_bit_cast(u32, __builtin_amdgcn_cvt_pkrtz(a, b));
    u[1] = __builtin_bit_cast(u32, __builtin_amdgcn_cvt_pkrtz(c, d));
    return __builtin_bit_cast(f16x4, u);
}
__device__ __forceinline__ f16x8 cat8(f16x4 lo, f16x4 hi){
    u32x2 a = __builtin_bit_cast(u32x2, lo), b = __builtin_bit_cast(u32x2, hi);
    u32x4 u; u[0] = a[0]; u[1] = a[1]; u[2] = b[0]; u[3] = b[1];
    return __builtin_bit_cast(f16x8, u);
}

#define MFMA32(a, b, c) __builtin_amdgcn_mfma_f32_32x32x16_f16((a), (b), (c), 0, 0, 0)

// ===== K-permutation pi (r9, HALF-DECOUPLED): k-slot (kc, 8h+j) holds feature
//       16*kc + 8*(j>>2) + 4*h + (j&3).
// Frags kc{0,1} carry ONLY t=0 output features, kc{2,3} ONLY t=1.
//
// r10: waves are phase-ALIGNED (single barrier, identical code, symmetric
// stalls) -> trans-pipe 4x-oversubscribed during act bursts while matrix pipe
// idles, and vice versa (r9: 20-25% no-issue with no pipe saturated). Fix:
// (1) one-time per-SIMD stagger after prep, (2) setprio(1) around MFMA
// clusters so a mid-chain wave wins arbitration once waves ARE offset (T5).
template<int ACTI, int NP>
__device__ __forceinline__ void node32(const f16* __restrict__ wr,   // &wfrag[ni][0][0][lane][0]
                                       const float* __restrict__ bs, // &b_s[ni][0] (prescaled)
                                       const int hf4,                // 4*(lane>>5)
                                       const f16x8 A0[4], const f16x8 A1[4], const f16x8 A2[4],
                                       f16x8 OUT[4])
{
    f32x16 a0, a1;
    #pragma unroll
    for (int g = 0; g < 4; ++g){
        f32x4 b0 = *(const f32x4*)(bs +      8 * g + hf4);
        f32x4 b1 = *(const f32x4*)(bs + 32 + 8 * g + hf4);
        a0[4*g+0] = b0[0]; a0[4*g+1] = b0[1]; a0[4*g+2] = b0[2]; a0[4*g+3] = b0[3];
        a1[4*g+0] = b1[0]; a1[4*g+1] = b1[1]; a1[4*g+2] = b1[2]; a1[4*g+3] = b1[3];
    }
    __builtin_amdgcn_s_setprio(1);
    #pragma unroll
    for (int kc = 0; kc < 4; ++kc){
        f16x8 bB = A0[kc];
        if constexpr (NP >= 2){ bB = bB + A1[kc]; }
        if constexpr (NP >= 3){ bB = bB + A2[kc]; }
        const f16x8 W0 = *(const f16x8*)(wr +        kc * 512);
        const f16x8 W1 = *(const f16x8*)(wr + 2048 + kc * 512);
        a0 = MFMA32(W0, bB, a0);
        a1 = MFMA32(W1, bB, a1);
    }
    __builtin_amdgcn_s_setprio(0);
    // t0 acts -> OUT[0..1] first, then t1 acts.
    f16x4 pk0[4], pk1[4];
    #pragma unroll
    for (int g = 0; g < 4; ++g){
        f32x2 o01 = act2<ACTI>(f32x2{a0[4*g+0], a0[4*g+1]});
        f32x2 o23 = act2<ACTI>(f32x2{a0[4*g+2], a0[4*g+3]});
        pk0[g] = pack4(o01.x, o01.y, o23.x, o23.y);
    }
    OUT[0] = cat8(pk0[0], pk0[1]);
    OUT[1] = cat8(pk0[2], pk0[3]);
    #pragma unroll
    for (int g = 0; g < 4; ++g){
        f32x2 o01 = act2<ACTI>(f32x2{a1[4*g+0], a1[4*g+1]});
        f32x2 o23 = act2<ACTI>(f32x2{a1[4*g+2], a1[4*g+3]});
        pk1[g] = pack4(o01.x, o01.y, o23.x, o23.y);
    }
    OUT[2] = cat8(pk1[0], pk1[1]);
    OUT[3] = cat8(pk1[2], pk1[3]);
}

// 1024-thread block (16 waves) + 106KB LDS -> 1 block/CU, 4 waves/SIMD.
__global__ __launch_bounds__(1024, 1) void inr_mfma8_kernel(
    const float* __restrict__ gx, const float* __restrict__ gy,
    const float* __restrict__ gz, const float* __restrict__ gr,
    const float* __restrict__ gnoise,
    const float* __restrict__ W_noise, const float* __restrict__ b_noise,
    const float* __restrict__ W_x, const float* __restrict__ W_y,
    const float* __restrict__ W_z, const float* __restrict__ W_r,
    const float* __restrict__ W1, const float* __restrict__ b1,
    const float* __restrict__ Wg, const float* __restrict__ bg,
    const float* __restrict__ W_out, const float* __restrict__ b_out,
    float* __restrict__ out, int nt, int niter)
{
    // ---- LDS ~106 KB, 1 block (16 waves) per CU -> 4 waves/SIMD ----
    __shared__ __align__(16) f16   wfrag[12][2][4][64][8]; // 96 KB  prescaled W^T A-frags, pi-permuted k
    __shared__ __align__(16) f16   nfrag[2][64][8];        //  2 KB  2log2e*W_noise^T
    __shared__ __align__(16) f16   ofrag[4][64][8];        //  4 KB  -log2e*W_out^T (pi, rows>=3 zero)
    __shared__ __align__(16) float b_s[12][64];            //  3 KB  prescaled biases
    __shared__ __align__(16) float wvs[4][64];             //  1 KB  [0]=C_GAU*Wx^2, [1]=2log2e*Wy, [2]=Wz, [3]=log2e*Wr
    __shared__ __align__(16) float bns[64];                //  256B  2log2e*b_noise
    __shared__            float bout_s[4];

    const int tid  = threadIdx.x;
    const int lane = tid & 63;
    const int n2   = lane & 31;      // point-in-tile (MFMA col)
    const int hf   = lane >> 5;      // half-wave
    const int hf4  = 4 * hf;

    // ================= PREP: barrier-free direct global->frag (grid=256 -> once per CU) ======
    if (tid < 768){
        int node = tid >> 6, f = tid & 63;
        b_s[node][f] = NSCL[node] * ((node == 0) ? b1[f] : bg[(node - 1) * 64 + f]);
    }
    if (tid < 256){
        int vec = tid >> 6, f = tid & 63;
        float v;
        if      (vec == 0){ float w = W_x[f]; v = C_GAU * w * w; }
        else if (vec == 1){ v = C_TANH * W_y[f]; }
        else if (vec == 2){ v = W_z[f]; }
        else              { v = LOG2E * W_r[f]; }
        wvs[vec][f] = v;
    }
    if (tid < 64) bns[tid] = C_TANH * b_noise[tid];
    if (tid < 4)  bout_s[tid] = (tid < 3) ? C_SIG * b_out[tid] : 0.0f;
    if (tid < 128){                                  // nfrag: A[m][k]=2log2e*W_noise[k][m], k=8h+j (no pi)
        int t = tid >> 6, ln = tid & 63, m = ln & 31, h = ln >> 5;
        f16x8 v;
        #pragma unroll
        for (int j = 0; j < 8; ++j) v[j] = (f16)(C_TANH * W_noise[(8 * h + j) * 64 + 32 * t + m]);
        *(f16x8*)&nfrag[t][ln][0] = v;
    }
    if (tid < 256){                                  // ofrag: A[m][k]=-log2e*W_out[pi][m] (m<3), pi r9
        int kc = tid >> 6, ln = tid & 63, m = ln & 31, h = ln >> 5;
        f16x8 v;
        #pragma unroll
        for (int j = 0; j < 8; ++j){
            int kf = 16 * kc + 8 * (j >> 2) + 4 * h + (j & 3);
            v[j] = (m < 3) ? (f16)(C_SIG * W_out[kf * 3 + m]) : (f16)0.0f;
        }
        *(f16x8*)&ofrag[kc][ln][0] = v;
    }
    // big weights, pi r9: kf = 16*kc + 8*(j>>2) + 4*h + (j&3)
    {
        const int sub = tid & 511;
        const int t = sub >> 8, kc = (sub >> 6) & 3, ln = sub & 63, m = ln & 31, h = ln >> 5;
        int kfo[8];
        #pragma unroll
        for (int j = 0; j < 8; ++j)
            kfo[j] = (16 * kc + 8 * (j >> 2) + 4 * h + (j & 3)) * 64 + 32 * t + m;
        #pragma unroll
        for (int node = tid >> 9; node < 12; node += 2){
            const float* Wsrc = (node == 0) ? W1 : (Wg + (node - 1) * 4096);
            const float  scl  = NSCL[node];
            f16x8 v;
            #pragma unroll
            for (int j = 0; j < 8; ++j) v[j] = (f16)(scl * Wsrc[kfo[j]]);
            *(f16x8*)&wfrag[node][t][kc][ln][0] = v;
        }
    }
    __syncthreads();   // single barrier: all fragments complete

    const int wvid = tid >> 6;       // wave id 0..15

    // ---- r10 STAGGER: wave w sits on SIMD w%4, so waves {s,s+4,s+8,s+12}
    // share a SIMD. Offset them by ~1K-cy steps (~1/4 of the input-stage trans
    // burst) so act bursts and MFMA chains interleave across waves instead of
    // colliding. No later barriers -> offset persists. Tail cost <=2%.
    {
        const int slot = wvid >> 2;  // 0..3, distinct per wave within a SIMD
        if      (slot == 1) asm volatile("s_sleep 16");   // ~1024 cy
        else if (slot == 2) asm volatile("s_sleep 32");   // ~2048 cy
        else if (slot == 3) asm volatile("s_sleep 48");   // ~3072 cy
    }

    #define WPTR(NI) (&wfrag[NI][0][0][lane][0])
    #define N1(NI, ACTI, A, OUT)        node32<ACTI,1>(WPTR(NI), &b_s[NI][0], hf4, A, A, A, OUT)
    #define N2(NI, ACTI, A, B, OUT)     node32<ACTI,2>(WPTR(NI), &b_s[NI][0], hf4, A, B, B, OUT)
    #define N3(NI, ACTI, A, B, C, OUT)  node32<ACTI,3>(WPTR(NI), &b_s[NI][0], hf4, A, B, C, OUT)

    // ================= MAIN LOOP: 1 tile (32 pts) per wave per iter =================
    for (int it = 0; it < niter; ++it){
        const int tile = (it * gridDim.x + blockIdx.x) * 16 + wvid;
        if (tile >= nt) break;
        const int myp = tile * 32 + n2;

        // ---- input stage -> ring buffer ra (dual-acc, packed plains, scalar trans) ----
        f16x8 ra[4];
        {
            const float xs = gx[myp], ys = gy[myp], zs = gz[myp], rs = gr[myp];
            const float xs2 = xs * xs;
            f16x8 nb;
            {
                const float4 a4 = *(const float4*)(gnoise + (size_t)myp * 16 + 8 * hf);
                const float4 b4 = *(const float4*)(gnoise + (size_t)myp * 16 + 8 * hf + 4);
                nb = cat8(pack4(a4.x, a4.y, a4.z, a4.w), pack4(b4.x, b4.y, b4.z, b4.w));
            }
            f32x16 ac0, ac1;
            #pragma unroll
            for (int i = 0; i < 16; ++i){ ac0[i] = 0.0f; ac1[i] = 0.0f; }
            ac0 = MFMA32(*(const f16x8*)&nfrag[0][lane][0], nb, ac0);
            ac1 = MFMA32(*(const f16x8*)&nfrag[1][lane][0], nb, ac1);
            f16x4 pkg[2][4];
            #pragma unroll
            for (int t = 0; t < 2; ++t){
                const f32x16& ac = t ? ac1 : ac0;       // constant after unroll
                #pragma unroll
                for (int g = 0; g < 4; ++g){
                    const int fb = 32 * t + 8 * g + hf4;
                    const f32x4 wx2 = *(const f32x4*)&wvs[0][fb];   // C_GAU*Wx^2
                    const f32x4 wyt = *(const f32x4*)&wvs[1][fb];   // 2log2e*Wy
                    const f32x4 wz  = *(const f32x4*)&wvs[2][fb];
                    const f32x4 wr_ = *(const f32x4*)&wvs[3][fb];   // log2e*Wr
                    const f32x4 bn  = *(const f32x4*)&bns[fb];      // 2log2e*b_noise
                    f32x2 sv[2];
                    #pragma unroll
                    for (int p = 0; p < 2; ++p){
                        const f32x2 z2 = {0.0f, 0.0f};
                        // elu(z)
                        f32x2 wzp = {wz[2*p], wz[2*p+1]};
                        f32x2 az  = zs * wzp;
                        f32x2 we  = az * LOG2E;
                        f32x2 ee  = {fexp2(we.x), fexp2(we.y)};
                        f32x2 em1 = ee - 1.0f;
                        f32x2 el  = __builtin_elementwise_max(az, z2)
                                  + __builtin_elementwise_min(em1, z2);
                        // gauss(x): exp2(xs2 * C_GAU*Wx^2)
                        f32x2 wxp = {wx2[2*p], wx2[2*p+1]};
                        f32x2 wg  = xs2 * wxp;
                        f32x2 ga  = {fexp2(wg.x), fexp2(wg.y)};
                        // tanh(y)
                        f32x2 wyp = {wyt[2*p], wyt[2*p+1]};
                        f32x2 wy  = ys * wyp;
                        f32x2 tty = {fexp2(wy.x), fexp2(wy.y)};
                        f32x2 uy  = tty + 1.0f;
                        f32x2 ry  = {frcp(uy.x), frcp(uy.y)};
                        f32x2 ty  = ry * -2.0f + 1.0f;
                        // softplus(r): LN2*log2(1+exp2(log2e*r*Wr))
                        f32x2 wrp = {wr_[2*p], wr_[2*p+1]};
                        f32x2 wsp = rs * wrp;
                        f32x2 es  = {fexp2(wsp.x), fexp2(wsp.y)};
                        f32x2 us  = es + 1.0f;
                        f32x2 ls  = {flog2(us.x), flog2(us.y)};
                        f32x2 sp  = ls * LN2;
                        // tanh(noise line)
                        f32x2 acp = {ac[4*g+2*p], ac[4*g+2*p+1]};
                        f32x2 bnp = {bn[2*p], bn[2*p+1]};
                        f32x2 wt  = acp + bnp;
                        f32x2 ttp = {fexp2(wt.x), fexp2(wt.y)};
                        f32x2 up  = ttp + 1.0f;
                        f32x2 rp  = {frcp(up.x), frcp(up.y)};
                        f32x2 tp  = rp * -2.0f + 1.0f;
                        // sum & sin
                        sv[p] = ((el + ga) + (ty + sp) + tp) * C_SIN;
                    }
                    pkg[t][g] = pack4(fsin1(sv[0].x), fsin1(sv[0].y),
                                      fsin1(sv[1].x), fsin1(sv[1].y));
                }
            }
            // pi assembly: frag kc <- pkg[kc>>1][2*(kc&1)], pkg[kc>>1][2*(kc&1)+1]
            ra[0] = cat8(pkg[0][0], pkg[0][1]);
            ra[1] = cat8(pkg[0][2], pkg[0][3]);
            ra[2] = cat8(pkg[1][0], pkg[1][1]);
            ra[3] = cat8(pkg[1][2], pkg[1][3]);
        }

        // ---- graph: 5-buffer ring (h0 + ra/rb/rc/rd), sg merged into ra ----
        f16x8 h0[4], rb[4], rc[4], rd[4];
        N1(0,  0, ra, h0);                 // h0 = tanh(g @ W1 + b1)
        N1(1,  0, h0, ra);                 // h1 = tanh(h0 W)
        N1(2,  1, ra, rb);                 // h2 = elu(h1 W)
        N2(3,  2, rb, h0, rc);             // h3 = softplus((h2+h0) W)
        N3(4,  3, rc, ra, h0, rd);         // h4 = sin((h3+h1+h0) W)
        N2(5,  4, rd, rb, ra);             // h5 = gauss((h4+h2) W)
        N2(6,  5, ra, rc, rb);             // h6 = sigmoid((h5+h3) W)
        N2(7,  0, rb, rd, rc);             // h7 = tanh((h6+h4) W)
        N3(8,  1, rc, ra, h0, rd);         // h8 = elu((h7+h5+h0) W)
        N2(9,  2, rd, rb, ra);             // h9 = softplus((h8+h6) W)
        N2(10, 3, ra, rc, rb);             // h10= sin((h9+h7) W)
        N2(11, 4, rb, rd, rc);             // h11= gauss((h10+h8) W)

        // ---- output: exact hw sigmoid folded into ofrag: out = rcp(1+exp2(om+bout)) ----
        {
            f32x16 om;
            #pragma unroll
            for (int i = 0; i < 16; ++i) om[i] = 0.0f;
            #pragma unroll
            for (int kc = 0; kc < 4; ++kc)
                om = MFMA32(*(const f16x8*)&ofrag[kc][lane][0], rc[kc], om);
            if (hf == 0){
                #pragma unroll
                for (int r = 0; r < 3; ++r)
                    out[(size_t)myp * 3 + r] = frcp(1.0f + fexp2(om[r] + bout_s[r]));
            }
        }
    }
    #undef N1
    #undef N2
    #undef N3
    #undef WPTR
}

extern "C" void kernel_launch(void* const* d_in, const int* in_sizes, int n_in,
                              void* d_out, int out_size, void* d_ws, size_t ws_size,
                              hipStream_t stream)
{
    const float* x       = (const float*)d_in[0];
    const float* y       = (const float*)d_in[1];
    const float* z       = (const float*)d_in[2];
    const float* r       = (const float*)d_in[3];
    const float* noise   = (const float*)d_in[4];
    const float* W_noise = (const float*)d_in[5];
    const float* b_noise = (const float*)d_in[6];
    const float* W_x     = (const float*)d_in[7];
    const float* W_y     = (const float*)d_in[8];
    const float* W_z     = (const float*)d_in[9];
    const float* W_r     = (const float*)d_in[10];
    const float* W1      = (const float*)d_in[11];
    const float* b1      = (const float*)d_in[12];
    const float* Wg      = (const float*)d_in[13];
    const float* bg      = (const float*)d_in[14];
    const float* W_out   = (const float*)d_in[15];
    const float* b_out   = (const float*)d_in[16];
    float* out = (float*)d_out;

    const int n     = in_sizes[0];
    const int nt    = n / 32;                       // 32-pt tiles (8192)
    const int grid  = 256;                          // 1 block per CU; prep once per CU
    const int tiles_per_pass = grid * 16;           // 16 waves x 1 tile = 4096 -> niter=2
    const int niter = (nt + tiles_per_pass - 1) / tiles_per_pass;
    inr_mfma8_kernel<<<dim3(grid), dim3(1024), 0, stream>>>(
        x, y, z, r, noise, W_noise, b_noise, W_x, W_y, W_z, W_r,
        W1, b1, Wg, bg, W_out, b_out, out, nt, niter);
}

// Round 11
// 152.015 us; speedup vs baseline: 1.0185x; 1.0185x over previous
//
#include <hip/hip_runtime.h>

typedef _Float16 f16;
typedef f16  f16x4 __attribute__((ext_vector_type(4)));
typedef f16  f16x8 __attribute__((ext_vector_type(8)));
typedef float f32x2  __attribute__((ext_vector_type(2)));
typedef float f32x4  __attribute__((ext_vector_type(4)));
typedef float f32x16 __attribute__((ext_vector_type(16)));
typedef unsigned int u32;
typedef u32 u32x2 __attribute__((ext_vector_type(2)));
typedef u32 u32x4 __attribute__((ext_vector_type(4)));

#define LOG2E   1.4426950408889634f
#define LN2     0.6931471805599453f
#define C_TANH  2.8853900817779268f    // 2*log2(e)
#define C_SIN   0.15915494309189535f   // 1/(2*pi)
#define C_SIG  -1.4426950408889634f    // -log2(e)
#define C_GAU  -0.7213475204444817f    // -log2(e)/2
#define C_GSQ   0.84932180028802f      // sqrt(log2(e)/2): gauss = exp2(-(s*u)^2)

// per-node arg prescale baked into W,b at prep: acts 0=tanh,1=elu,2=softplus,3=sin,4=gauss,5=sigmoid
// tanh: 2log2e bake; sigmoid: 2log2e bake via tanh form? NO -- sigmoid node uses
// C_SIG bake with batched form below operating on exp2(v), v = -log2e*x:
// sigma = 1/(1+exp2(v)). tanh: 1 - 2/(1+exp2(v)), v = 2log2e*x.
__device__ __constant__ float NSCL[12] = {
    C_TANH, C_TANH, 1.0f, LOG2E, C_SIN, C_GSQ, C_SIG, C_TANH, 1.0f, LOG2E, C_SIN, C_GSQ
};

__device__ __forceinline__ float frcp(float x){ return __builtin_amdgcn_rcpf(x); }
__device__ __forceinline__ float fexp2(float x){ return __builtin_amdgcn_exp2f(x); }
__device__ __forceinline__ float flog2(float x){ return __builtin_amdgcn_logf(x); }
__device__ __forceinline__ float fsin1(float x){ return __builtin_amdgcn_sinf(x); } // arg in revolutions

// ---------- PAIR-PACKED activations on PRESCALED args (see NSCL) ----------
// r5/r8 calibration: trans ~8cy, packed plain ~2cy. r11: tanh/sigmoid use a
// BATCHED reciprocal -- rcp(u1*u2) shared by two evals: 2 rcp (16cy) ->
// 1 rcp + 3 pk-mul (~14cy... net -10cy/pair after packing). Overflow-safe:
// graph pre-acts <=~16 -> u1*u2 <= 2^92 << f32 max; saturating case returns
// the correct tanh=+-1 anyway (rr->0 -> o->1).
template<int A> __device__ __forceinline__ f32x2 act2(f32x2 v){
    if constexpr (A == 1){                       // elu; v raw: max(v,0)+min(e-1,0)
        f32x2 w = v * LOG2E;
        f32x2 e = {fexp2(w.x), fexp2(w.y)};
        f32x2 em1 = e - 1.0f;
        f32x2 z = {0.0f, 0.0f};
        return __builtin_elementwise_max(v, z) + __builtin_elementwise_min(em1, z);
    } else if constexpr (A == 2){                // softplus; v = log2e*x
        f32x2 e = {fexp2(v.x), fexp2(v.y)};
        f32x2 u = e + 1.0f;
        f32x2 l = {flog2(u.x), flog2(u.y)};
        return l * LN2;
    } else if constexpr (A == 3){                // sin; v = x/(2pi)
        return f32x2{fsin1(v.x), fsin1(v.y)};
    } else {                                     // gauss; v = sqrt(log2e/2)*x
        f32x2 w = -(v * v);
        return f32x2{fexp2(w.x), fexp2(w.y)};
    }
}

__device__ __forceinline__ f16x4 pack4(float a, float b, float c, float d){
    u32x2 u;
    u[0] = __builtin_bit_cast(u32, __builtin_amdgcn_cvt_pkrtz(a, b));
    u[1] = __builtin_bit_cast(u32, __builtin_amdgcn_cvt_pkrtz(c, d));
    return __builtin_bit_cast(f16x4, u);
}
__device__ __forceinline__ f16x8 cat8(f16x4 lo, f16x4 hi){
    u32x2 a = __builtin_bit_cast(u32x2, lo), b = __builtin_bit_cast(u32x2, hi);
    u32x4 u; u[0] = a[0]; u[1] = a[1]; u[2] = b[0]; u[3] = b[1];
    return __builtin_bit_cast(f16x8, u);
}

#define MFMA32(a, b, c) __builtin_amdgcn_mfma_f32_32x32x16_f16((a), (b), (c), 0, 0, 0)

// K-permutation pi: k-slot (kc, 8h+j) holds feature 8*kc + 32*(j>>2) + 4*h + (j&3);
// next node's B-frag[kc] = cat(pk[t=0][g=kc], pk[t=1][g=kc]) -- registers only.
//
// SINGLE-tile node (one 32-pt tile per wave): 16-wave workgroup caps the unified
// register budget at 128/wave (64 arch VGPR + 64 AGPR with MFMA).
// r7: keep pred sums as pk_f16 adds (MFMA-sum lengthened the chain, spilled).
// r10: NO setprio (it fences the scheduler -> +13MB spills) and no stagger.
template<int ACTI, int NP>
__device__ __forceinline__ void node32(const f16* __restrict__ wr,   // &wfrag[ni][0][0][lane][0]
                                       const float* __restrict__ bs, // &b_s[ni][0] (prescaled)
                                       const int hf4,                // 4*(lane>>5)
                                       const f16x8 A0[4], const f16x8 A1[4], const f16x8 A2[4],
                                       f16x8 OUT[4])
{
    f16x4 pk[2][4];
    #pragma unroll
    for (int t = 0; t < 2; ++t){
        f32x16 a;
        #pragma unroll
        for (int g = 0; g < 4; ++g){
            f32x4 bv = *(const f32x4*)(bs + 32 * t + 8 * g + hf4);
            a[4*g+0] = bv[0]; a[4*g+1] = bv[1]; a[4*g+2] = bv[2]; a[4*g+3] = bv[3];
        }
        #pragma unroll
        for (int kc = 0; kc < 4; ++kc){
            f16x8 Af = *(const f16x8*)(wr + t * 2048 + kc * 512);
            f16x8 bB = A0[kc];
            if constexpr (NP >= 2){ bB = bB + A1[kc]; }
            if constexpr (NP >= 3){ bB = bB + A2[kc]; }
            a = MFMA32(Af, bB, a);
        }
        #pragma unroll
        for (int g = 0; g < 4; ++g){
            f32x2 v01 = {a[4*g+0], a[4*g+1]};
            f32x2 v23 = {a[4*g+2], a[4*g+3]};
            f32x2 o01, o23;
            if constexpr (ACTI == 0 || ACTI == 5){
                // batched-rcp tanh / sigmoid (one rcp pair serves 4 evals)
                f32x2 e01 = {fexp2(v01.x), fexp2(v01.y)};
                f32x2 e23 = {fexp2(v23.x), fexp2(v23.y)};
                f32x2 u01 = e01 + 1.0f, u23 = e23 + 1.0f;
                f32x2 pr  = u01 * u23;
                f32x2 rr  = {frcp(pr.x), frcp(pr.y)};
                f32x2 r01 = u23 * rr, r23 = u01 * rr;
                if constexpr (ACTI == 0){ o01 = r01 * -2.0f + 1.0f; o23 = r23 * -2.0f + 1.0f; }
                else                    { o01 = r01;                o23 = r23; }
            } else {
                o01 = act2<ACTI>(v01);
                o23 = act2<ACTI>(v23);
            }
            pk[t][g] = pack4(o01.x, o01.y, o23.x, o23.y);
        }
    }
    #pragma unroll
    for (int kc = 0; kc < 4; ++kc)
        OUT[kc] = cat8(pk[0][kc], pk[1][kc]);
}

// 1024-thread block (16 waves) + 106KB LDS -> 1 block/CU, 4 waves/SIMD.
__global__ __launch_bounds__(1024, 1) void inr_mfma8_kernel(
    const float* __restrict__ gx, const float* __restrict__ gy,
    const float* __restrict__ gz, const float* __restrict__ gr,
    const float* __restrict__ gnoise,
    const float* __restrict__ W_noise, const float* __restrict__ b_noise,
    const float* __restrict__ W_x, const float* __restrict__ W_y,
    const float* __restrict__ W_z, const float* __restrict__ W_r,
    const float* __restrict__ W1, const float* __restrict__ b1,
    const float* __restrict__ Wg, const float* __restrict__ bg,
    const float* __restrict__ W_out, const float* __restrict__ b_out,
    float* __restrict__ out, int nt, int niter)
{
    // ---- LDS ~106 KB, 1 block (16 waves) per CU -> 4 waves/SIMD ----
    __shared__ __align__(16) f16   wfrag[12][2][4][64][8]; // 96 KB  prescaled W^T A-frags, pi-permuted k
    __shared__ __align__(16) f16   nfrag[2][64][8];        //  2 KB  2log2e*W_noise^T
    __shared__ __align__(16) f16   ofrag[4][64][8];        //  4 KB  -log2e*W_out^T (pi, rows>=3 zero)
    __shared__ __align__(16) float b_s[12][64];            //  3 KB  prescaled biases
    __shared__ __align__(16) float wvs[4][64];             //  1 KB  [0]=C_GAU*Wx^2, [1]=2log2e*Wy, [2]=Wz, [3]=log2e*Wr
    __shared__ __align__(16) float bns[64];                //  256B  2log2e*b_noise
    __shared__            float bout_s[4];

    const int tid  = threadIdx.x;
    const int lane = tid & 63;
    const int n2   = lane & 31;      // point-in-tile (MFMA col)
    const int hf   = lane >> 5;      // half-wave
    const int hf4  = 4 * hf;

    // ================= PREP: barrier-free direct global->frag (grid=256 -> once per CU) ======
    if (tid < 768){
        int node = tid >> 6, f = tid & 63;
        b_s[node][f] = NSCL[node] * ((node == 0) ? b1[f] : bg[(node - 1) * 64 + f]);
    }
    if (tid < 256){
        int vec = tid >> 6, f = tid & 63;
        float v;
        if      (vec == 0){ float w = W_x[f]; v = C_GAU * w * w; }
        else if (vec == 1){ v = C_TANH * W_y[f]; }
        else if (vec == 2){ v = W_z[f]; }
        else              { v = LOG2E * W_r[f]; }
        wvs[vec][f] = v;
    }
    if (tid < 64) bns[tid] = C_TANH * b_noise[tid];
    if (tid < 4)  bout_s[tid] = (tid < 3) ? C_SIG * b_out[tid] : 0.0f;
    if (tid < 128){                                  // nfrag: A[m][k]=2log2e*W_noise[k][m], k=8h+j
        int t = tid >> 6, ln = tid & 63, m = ln & 31, h = ln >> 5;
        f16x8 v;
        #pragma unroll
        for (int j = 0; j < 8; ++j) v[j] = (f16)(C_TANH * W_noise[(8 * h + j) * 64 + 32 * t + m]);
        *(f16x8*)&nfrag[t][ln][0] = v;
    }
    if (tid < 256){                                  // ofrag: A[m][k]=-log2e*W_out[pi][m] (m<3)
        int kc = tid >> 6, ln = tid & 63, m = ln & 31, h = ln >> 5;
        f16x8 v;
        #pragma unroll
        for (int j = 0; j < 8; ++j){
            int kf = 8 * kc + 32 * (j >> 2) + 4 * h + (j & 3);
            v[j] = (m < 3) ? (f16)(C_SIG * W_out[kf * 3 + m]) : (f16)0.0f;
        }
        *(f16x8*)&ofrag[kc][ln][0] = v;
    }
    // big weights: 1024 threads cover the 512 frag slots twice -> each half does 6 nodes,
    // straight from global (L2-hot), one ds_write_b128 each, NO intermediate barriers
    {
        const int sub = tid & 511;
        const int t = sub >> 8, kc = (sub >> 6) & 3, ln = sub & 63, m = ln & 31, h = ln >> 5;
        int kfo[8];
        #pragma unroll
        for (int j = 0; j < 8; ++j)
            kfo[j] = (8 * kc + 32 * (j >> 2) + 4 * h + (j & 3)) * 64 + 32 * t + m;
        #pragma unroll
        for (int node = tid >> 9; node < 12; node += 2){
            const float* Wsrc = (node == 0) ? W1 : (Wg + (node - 1) * 4096);
            const float  scl  = NSCL[node];
            f16x8 v;
            #pragma unroll
            for (int j = 0; j < 8; ++j) v[j] = (f16)(scl * Wsrc[kfo[j]]);
            *(f16x8*)&wfrag[node][t][kc][ln][0] = v;
        }
    }
    __syncthreads();   // single barrier: all fragments complete

    #define WPTR(NI) (&wfrag[NI][0][0][lane][0])
    #define N1(NI, ACTI, A, OUT)        node32<ACTI,1>(WPTR(NI), &b_s[NI][0], hf4, A, A, A, OUT)
    #define N2(NI, ACTI, A, B, OUT)     node32<ACTI,2>(WPTR(NI), &b_s[NI][0], hf4, A, B, B, OUT)
    #define N3(NI, ACTI, A, B, C, OUT)  node32<ACTI,3>(WPTR(NI), &b_s[NI][0], hf4, A, B, C, OUT)

    const int wvid = tid >> 6;       // wave id 0..15

    // ================= MAIN LOOP: 1 tile (32 pts) per wave per iter =================
    for (int it = 0; it < niter; ++it){
        const int tile = (it * gridDim.x + blockIdx.x) * 16 + wvid;
        if (tile >= nt) break;
        const int myp = tile * 32 + n2;

        // ---- input stage -> ring buffer ra (packed plains, scalar trans, batched rcp) ----
        f16x8 ra[4];
        {
            const float xs = gx[myp], ys = gy[myp], zs = gz[myp], rs = gr[myp];
            const float xs2 = xs * xs;
            f16x8 nb;
            {
                const float4 a4 = *(const float4*)(gnoise + (size_t)myp * 16 + 8 * hf);
                const float4 b4 = *(const float4*)(gnoise + (size_t)myp * 16 + 8 * hf + 4);
                nb = cat8(pack4(a4.x, a4.y, a4.z, a4.w), pack4(b4.x, b4.y, b4.z, b4.w));
            }
            f16x4 pkg[2][4];
            #pragma unroll
            for (int t = 0; t < 2; ++t){
                f32x16 ac;
                #pragma unroll
                for (int i = 0; i < 16; ++i) ac[i] = 0.0f;
                ac = MFMA32(*(const f16x8*)&nfrag[t][lane][0], nb, ac);
                #pragma unroll
                for (int g = 0; g < 4; ++g){
                    const int fb = 32 * t + 8 * g + hf4;
                    const f32x4 wx2 = *(const f32x4*)&wvs[0][fb];   // C_GAU*Wx^2
                    const f32x4 wyt = *(const f32x4*)&wvs[1][fb];   // 2log2e*Wy
                    const f32x4 wz  = *(const f32x4*)&wvs[2][fb];
                    const f32x4 wr_ = *(const f32x4*)&wvs[3][fb];   // log2e*Wr
                    const f32x4 bn  = *(const f32x4*)&bns[fb];      // 2log2e*b_noise
                    f32x2 sv[2];
                    #pragma unroll
                    for (int p = 0; p < 2; ++p){
                        const f32x2 z2 = {0.0f, 0.0f};
                        // elu(z)
                        f32x2 wzp = {wz[2*p], wz[2*p+1]};
                        f32x2 az  = zs * wzp;
                        f32x2 we  = az * LOG2E;
                        f32x2 ee  = {fexp2(we.x), fexp2(we.y)};
                        f32x2 em1 = ee - 1.0f;
                        f32x2 el  = __builtin_elementwise_max(az, z2)
                                  + __builtin_elementwise_min(em1, z2);
                        // gauss(x): exp2(xs2 * C_GAU*Wx^2)
                        f32x2 wxp = {wx2[2*p], wx2[2*p+1]};
                        f32x2 wg  = xs2 * wxp;
                        f32x2 ga  = {fexp2(wg.x), fexp2(wg.y)};
                        // softplus(r): LN2*log2(1+exp2(log2e*r*Wr))
                        f32x2 wrp = {wr_[2*p], wr_[2*p+1]};
                        f32x2 wsp = rs * wrp;
                        f32x2 es  = {fexp2(wsp.x), fexp2(wsp.y)};
                        f32x2 us  = es + 1.0f;
                        f32x2 ls  = {flog2(us.x), flog2(us.y)};
                        f32x2 sp  = ls * LN2;
                        // tanh(y) and tanh(noise line) with BATCHED rcp:
                        //   uy,up <= 2^37 each -> product <= 2^74, no overflow
                        f32x2 wyp = {wyt[2*p], wyt[2*p+1]};
                        f32x2 wy  = ys * wyp;
                        f32x2 tty = {fexp2(wy.x), fexp2(wy.y)};
                        f32x2 acp = {ac[4*g+2*p], ac[4*g+2*p+1]};
                        f32x2 bnp = {bn[2*p], bn[2*p+1]};
                        f32x2 wt  = acp + bnp;
                        f32x2 ttp = {fexp2(wt.x), fexp2(wt.y)};
                        f32x2 uy  = tty + 1.0f;
                        f32x2 up  = ttp + 1.0f;
                        f32x2 pr  = uy * up;
                        f32x2 rr  = {frcp(pr.x), frcp(pr.y)};
                        f32x2 ty  = (up * rr) * -2.0f + 1.0f;
                        f32x2 tp  = (uy * rr) * -2.0f + 1.0f;
                        // sum & sin
                        sv[p] = ((el + ga) + (ty + sp) + tp) * C_SIN;
                    }
                    pkg[t][g] = pack4(fsin1(sv[0].x), fsin1(sv[0].y),
                                      fsin1(sv[1].x), fsin1(sv[1].y));
                }
            }
            #pragma unroll
            for (int kc = 0; kc < 4; ++kc) ra[kc] = cat8(pkg[0][kc], pkg[1][kc]);
        }

        // ---- graph: 5-buffer ring (h0 + ra/rb/rc/rd), sg merged into ra ----
        f16x8 h0[4], rb[4], rc[4], rd[4];
        N1(0,  0, ra, h0);                 // h0 = tanh(g @ W1 + b1)
        N1(1,  0, h0, ra);                 // h1 = tanh(h0 W)
        N1(2,  1, ra, rb);                 // h2 = elu(h1 W)
        N2(3,  2, rb, h0, rc);             // h3 = softplus((h2+h0) W)
        N3(4,  3, rc, ra, h0, rd);         // h4 = sin((h3+h1+h0) W)
        N2(5,  4, rd, rb, ra);             // h5 = gauss((h4+h2) W)
        N2(6,  5, ra, rc, rb);             // h6 = sigmoid((h5+h3) W)
        N2(7,  0, rb, rd, rc);             // h7 = tanh((h6+h4) W)
        N3(8,  1, rc, ra, h0, rd);         // h8 = elu((h7+h5+h0) W)
        N2(9,  2, rd, rb, ra);             // h9 = softplus((h8+h6) W)
        N2(10, 3, ra, rc, rb);             // h10= sin((h9+h7) W)
        N2(11, 4, rb, rd, rc);             // h11= gauss((h10+h8) W)

        // ---- output: exact hw sigmoid folded into ofrag: out = rcp(1+exp2(om+bout)) ----
        {
            f32x16 om;
            #pragma unroll
            for (int i = 0; i < 16; ++i) om[i] = 0.0f;
            #pragma unroll
            for (int kc = 0; kc < 4; ++kc)
                om = MFMA32(*(const f16x8*)&ofrag[kc][lane][0], rc[kc], om);
            if (hf == 0){
                #pragma unroll
                for (int r = 0; r < 3; ++r)
                    out[(size_t)myp * 3 + r] = frcp(1.0f + fexp2(om[r] + bout_s[r]));
            }
        }
    }
    #undef N1
    #undef N2
    #undef N3
    #undef WPTR
}

extern "C" void kernel_launch(void* const* d_in, const int* in_sizes, int n_in,
                              void* d_out, int out_size, void* d_ws, size_t ws_size,
                              hipStream_t stream)
{
    const float* x       = (const float*)d_in[0];
    const float* y       = (const float*)d_in[1];
    const float* z       = (const float*)d_in[2];
    const float* r       = (const float*)d_in[3];
    const float* noise   = (const float*)d_in[4];
    const float* W_noise = (const float*)d_in[5];
    const float* b_noise = (const float*)d_in[6];
    const float* W_x     = (const float*)d_in[7];
    const float* W_y     = (const float*)d_in[8];
    const float* W_z     = (const float*)d_in[9];
    const float* W_r     = (const float*)d_in[10];
    const float* W1      = (const float*)d_in[11];
    const float* b1      = (const float*)d_in[12];
    const float* Wg      = (const float*)d_in[13];
    const float* bg      = (const float*)d_in[14];
    const float* W_out   = (const float*)d_in[15];
    const float* b_out   = (const float*)d_in[16];
    float* out = (float*)d_out;

    const int n     = in_sizes[0];
    const int nt    = n / 32;                       // 32-pt tiles (8192)
    const int grid  = 256;                          // 1 block per CU; prep once per CU
    const int tiles_per_pass = grid * 16;           // 16 waves x 1 tile = 4096 -> niter=2
    const int niter = (nt + tiles_per_pass - 1) / tiles_per_pass;
    inr_mfma8_kernel<<<dim3(grid), dim3(1024), 0, stream>>>(
        x, y, z, r, noise, W_noise, b_noise, W_x, W_y, W_z, W_r,
        W1, b1, Wg, bg, W_out, b_out, out, nt, niter);
}